// Round 8
// baseline (318.488 us; speedup 1.0000x reference)
//
#include <hip/hip_runtime.h>
#include <math.h>

// FNO2d: B=4, C=3, H=W=256, L=4, WIDTH=32, M1=M2=12
// R8: (a) amdgpu_waves_per_eu(2,4) on k_dinvf/k_dinvmlp — cap the scheduler's
// occupancy TARGET (launch_bounds' 2nd arg only raises the register cap, which
// is why R7 was a no-op: VGPR stayed 44 with AGPR-copy inflation).
// (b) 4-way ILP in all dot-product chains (o-loop, MLP k-loop, DFT tails).
//
// ws layout (floats):
//   wpk [4624]     : packed MLP weights [k][32*w0 | b0 | w1*3], +b1 at end
//   cwp [4608]     : packed bypass weights [l][o][32*cw | cb | pad3]
//   h   [8388608]  : activations (B,32,H,W), in place per layer
//   tmp [786432]   : ky-DFT out (B,32,H,12) complex; ALIASED with g
//   hfp [294912]   : 4 x-partials of (B,32,24,12) complex

#define ANG0 0.024543692606170260f  // 2*pi/256

__device__ __forceinline__ float fgelu(float v) {
    // exact-GELU via A&S 7.1.26 erf approx, |err| <= 1.5e-7, branchless
    float u = v * 0.70710678118f;
    float a = fabsf(u);
    float t = __builtin_amdgcn_rcpf(__builtin_fmaf(0.3275911f, a, 1.0f));
    float p = t * __builtin_fmaf(t, __builtin_fmaf(t, __builtin_fmaf(t,
                  __builtin_fmaf(t, 1.061405429f, -1.453152027f),
                  1.421413741f), -0.284496736f), 0.254829592f);
    float e = __expf(-u * u);
    float er = __builtin_fmaf(-p, e, 1.0f);
    er = copysignf(er, u);
    return 0.5f * v * (1.0f + er);
}

__device__ __forceinline__ void fill_csp(float2* sCSP, int tid, int nthr) {
    for (int p = tid; p < 256; p += nthr)
        sCSP[p] = make_float2(cosf(p * ANG0), sinf(p * ANG0));
}

// ky-forward DFT over one (b,x) column held in sV[o*257 + y].
// Symmetric pairs, 4 independent accumulator chains.
__device__ __forceinline__ void ky_dft_tail(const float* sV, const float2* sCSP,
                                            float* tmp, int b, int x, int y) {
    for (int idx = y; idx < 384; idx += 256) {
        int o = idx / 12, ky = idx % 12;
        const float* vp = sV + o * 257;
        float v128 = vp[128];
        float aR0 = vp[0] + ((ky & 1) ? -v128 : v128);
        float aR1 = 0.f, aI0 = 0.f, aI1 = 0.f;
#pragma unroll 4
        for (int yy = 1; yy <= 125; yy += 2) {
            int p0 = (ky * yy) & 255;
            int p1 = (p0 + ky) & 255;
            float2 c0 = sCSP[p0], c1 = sCSP[p1];
            float fw0 = vp[yy],     bw0 = vp[256 - yy];
            float fw1 = vp[yy + 1], bw1 = vp[255 - yy];
            aR0 = __builtin_fmaf(fw0 + bw0, c0.x, aR0);
            aI0 = __builtin_fmaf(fw0 - bw0, -c0.y, aI0);
            aR1 = __builtin_fmaf(fw1 + bw1, c1.x, aR1);
            aI1 = __builtin_fmaf(fw1 - bw1, -c1.y, aI1);
        }
        {   // yy = 127 remainder
            int p = (ky * 127) & 255;
            float2 c = sCSP[p];
            float fw = vp[127], bw = vp[129];
            aR0 = __builtin_fmaf(fw + bw, c.x, aR0);
            aI0 = __builtin_fmaf(fw - bw, -c.y, aI0);
        }
        reinterpret_cast<float2*>(tmp + (((size_t)(b * 32 + o)) * 256 + x) * 24)[ky] =
            make_float2(aR0 + aR1, aI0 + aI1);
    }
}

__global__ void k_init(const float* __restrict__ w0, const float* __restrict__ b0,
                       const float* __restrict__ w1, const float* __restrict__ b1,
                       const float* __restrict__ cw, const float* __restrict__ cb,
                       float* __restrict__ wpk, float* __restrict__ cwp) {
    int t = threadIdx.x;
    for (int idx = t; idx < 128 * 36; idx += 256) {
        int k = idx / 36, j = idx - k * 36;
        float v;
        if (j < 32)       v = w0[j * 128 + k];
        else if (j == 32) v = b0[k];
        else              v = w1[k * 3 + (j - 33)];
        wpk[idx] = v;
    }
    if (t < 3) wpk[128 * 36 + t] = b1[t];
    for (int idx = t; idx < 4 * 32 * 36; idx += 256) {
        int lo = idx / 36, j = idx - lo * 36;
        int l = lo >> 5, o = lo & 31;
        float v = 0.f;
        if (j < 32)       v = cw[l * 1024 + j * 32 + o];
        else if (j == 32) v = cb[l * 32 + o];
        cwp[idx] = v;
    }
}

// Lift + ky-forward DFT for layer 0.
__global__ __launch_bounds__(256, 4) void k_liftf(const float* __restrict__ xin,
                                                  const float* __restrict__ pw,
                                                  const float* __restrict__ pb,
                                                  float* __restrict__ h,
                                                  float* __restrict__ tmp) {
    __shared__ float sV[32 * 257];
    __shared__ float2 sCSP[256];
    int b = blockIdx.x >> 8, x = blockIdx.x & 255, y = threadIdx.x;
    fill_csp(sCSP, y, 256);
    float f0 = xin[((b * 3 + 0) * 256 + x) * 256 + y];
    float f1 = xin[((b * 3 + 1) * 256 + x) * 256 + y];
    float f2 = xin[((b * 3 + 2) * 256 + x) * 256 + y];
    float gx = x * (1.0f / 255.0f), gy = y * (1.0f / 255.0f);
#pragma unroll
    for (int o = 0; o < 32; ++o) {
        float v = pb[o] + f0 * pw[o] + f1 * pw[32 + o] + f2 * pw[64 + o]
                + gx * pw[96 + o] + gy * pw[128 + o];
        h[((b * 32 + o) * 256 + x) * 256 + y] = v;
        sV[o * 257 + y] = v;
    }
    __syncthreads();
    ky_dft_tail(sV, sCSP, tmp, b, x, y);
}

// kx-forward DFT (4-way x-split): hfp[part][plane][kxi][ky]
__global__ __launch_bounds__(320) void k_dftx(const float* __restrict__ tmp,
                                              float* __restrict__ hfp) {
    __shared__ float sT[1536];
    __shared__ float2 sCSP[256];
    int plane = blockIdx.x >> 2, part = blockIdx.x & 3;
    int x0 = part * 64;
    int tid = threadIdx.x;
    fill_csp(sCSP, tid, 320);
    for (int idx = tid; idx < 1536; idx += 320)
        sT[idx] = tmp[(size_t)plane * 6144 + x0 * 24 + idx];
    __syncthreads();
    if (tid < 288) {
        int kxi = tid / 12, ky = tid % 12;
        int kxv = kxi < 12 ? kxi : 232 + kxi;
        float aR = 0.f, aI = 0.f;
        for (int xp = 0; xp < 64; ++xp) {
            int p = (kxv * (x0 + xp)) & 255;
            float2 cs2 = sCSP[p];
            float tr = sT[xp * 24 + 2 * ky], ti = sT[xp * 24 + 2 * ky + 1];
            aR += tr * cs2.x + ti * cs2.y;
            aI += ti * cs2.x - tr * cs2.y;
        }
        hfp[(((size_t)part * 128 + plane) * 24 + kxi) * 24 + 2 * ky]     = aR;
        hfp[(((size_t)part * 128 + plane) * 24 + kxi) * 24 + 2 * ky + 1] = aI;
    }
}

// Mode mix + kx-inverse, one block per (b,o).
__global__ __launch_bounds__(320) void k_mixcinv(const float* __restrict__ hfp,
                                                 const float* __restrict__ w1r,
                                                 const float* __restrict__ w1i,
                                                 const float* __restrict__ w2r,
                                                 const float* __restrict__ w2i,
                                                 float* __restrict__ g, int l) {
    __shared__ float sA[576];
    __shared__ float2 sCSP[256];
    int b = blockIdx.x >> 5, o = blockIdx.x & 31;
    int tid = threadIdx.x;
    fill_csp(sCSP, tid, 320);
    if (tid < 288) {
        int kxi = tid / 12, ky = tid % 12;
        const float *wr, *wi;
        int rk;
        if (kxi < 12) { wr = w1r; wi = w1i; rk = kxi; }
        else          { wr = w2r; wi = w2i; rk = kxi - 12; }
        size_t wbase = ((size_t)l * 32 * 32) * 144 + (size_t)o * 144 + rk * 12 + ky;
        size_t hbase = (((size_t)(b * 32)) * 24 + kxi) * 24 + 2 * ky;
        float aR = 0.f, aI = 0.f;
#pragma unroll 4
        for (int i = 0; i < 32; ++i) {
            float2 h0 = *reinterpret_cast<const float2*>(hfp + hbase + i * 576);
            float2 h1 = *reinterpret_cast<const float2*>(hfp + 73728 + hbase + i * 576);
            float2 h2 = *reinterpret_cast<const float2*>(hfp + 147456 + hbase + i * 576);
            float2 h3 = *reinterpret_cast<const float2*>(hfp + 221184 + hbase + i * 576);
            float hr = h0.x + h1.x + h2.x + h3.x;
            float hi = h0.y + h1.y + h2.y + h3.y;
            float wrv = wr[wbase + (size_t)i * 4608];
            float wiv = wi[wbase + (size_t)i * 4608];
            aR += hr * wrv - hi * wiv;
            aI += hr * wiv + hi * wrv;
        }
        sA[kxi * 24 + 2 * ky]     = aR;
        sA[kxi * 24 + 2 * ky + 1] = aI;
    }
    __syncthreads();
    if (tid < 256) {
        int x = tid;
        float out[24];
#pragma unroll
        for (int j = 0; j < 24; ++j) out[j] = 0.f;
        for (int kxi = 0; kxi < 24; ++kxi) {
            int kxv = kxi < 12 ? kxi : 232 + kxi;
            int p = (kxv * x) & 255;
            float2 cs2 = sCSP[p];
#pragma unroll
            for (int ky = 0; ky < 12; ++ky) {
                float ar = sA[kxi * 24 + 2 * ky], ai = sA[kxi * 24 + 2 * ky + 1];
                out[2 * ky]     += ar * cs2.x - ai * cs2.y;
                out[2 * ky + 1] += ar * cs2.y + ai * cs2.x;
            }
        }
        float* gp = g + ((size_t)(b * 32 + o)) * 6144 + x * 24;
#pragma unroll
        for (int j = 0; j < 24; ++j) gp[j] = out[j];
    }
}

// Layers 0..2: bypass+spectral+gelu, in-place h, + next-layer ky-DFT.
// g aliases tmp: all g reads precede the barrier; tail writes after.
__attribute__((amdgpu_waves_per_eu(2, 4)))
__global__ __launch_bounds__(256) void k_dinvf(float* __restrict__ h,
                                               const float* __restrict__ g,
                                               const float* __restrict__ cwp,
                                               float* __restrict__ tmp,
                                               int l) {
    __shared__ float sV[32 * 257];
    __shared__ float2 sCSP[256];
    int b = blockIdx.x >> 8, x = blockIdx.x & 255;
    int y = threadIdx.x;
    fill_csp(sCSP, y, 256);
    float hreg[32];
#pragma unroll
    for (int i = 0; i < 32; ++i)
        hreg[i] = h[(((size_t)(b * 32 + i)) * 256 + x) * 256 + y];
    __syncthreads();
    float ck[12], sk[12];
#pragma unroll
    for (int ky = 1; ky < 12; ++ky) {
        int p = (ky * y) & 255;
        float2 cs2 = sCSP[p];
        ck[ky] = 2.0f * cs2.x; sk[ky] = 2.0f * cs2.y;
    }
    const float* gb = g + ((size_t)(b * 32) * 256 + x) * 24;
    const float* wb = cwp + l * 32 * 36;
    for (int o = 0; o < 32; ++o) {
        const float* gp = gb + (size_t)o * 6144;   // uniform address
        const float* wp = wb + o * 36;             // uniform address
        float sc0 = gp[0], sc1 = 0.f, ss0 = 0.f, ss1 = 0.f;
#pragma unroll
        for (int ky = 1; ky < 12; ky += 2) {
            sc0 = __builtin_fmaf(gp[2 * ky], ck[ky], sc0);
            ss0 = __builtin_fmaf(gp[2 * ky + 1], sk[ky], ss0);
        }
#pragma unroll
        for (int ky = 2; ky < 12; ky += 2) {
            sc1 = __builtin_fmaf(gp[2 * ky], ck[ky], sc1);
            ss1 = __builtin_fmaf(gp[2 * ky + 1], sk[ky], ss1);
        }
        float spec = (sc0 + sc1) - (ss0 + ss1);
        float va0 = __builtin_fmaf(spec, 1.0f / 65536.0f, wp[32]);
        float va1 = 0.f, va2 = 0.f, va3 = 0.f;
#pragma unroll
        for (int i = 0; i < 32; i += 4) {
            va0 = __builtin_fmaf(hreg[i],     wp[i],     va0);
            va1 = __builtin_fmaf(hreg[i + 1], wp[i + 1], va1);
            va2 = __builtin_fmaf(hreg[i + 2], wp[i + 2], va2);
            va3 = __builtin_fmaf(hreg[i + 3], wp[i + 3], va3);
        }
        float v = (va0 + va1) + (va2 + va3);
        v = fgelu(v);
        h[(((size_t)(b * 32 + o)) * 256 + x) * 256 + y] = v;
        sV[o * 257 + y] = v;
    }
    __syncthreads();
    ky_dft_tail(sV, sCSP, tmp, b, x, y);
}

// Layer 3 (no gelu, no DFT) fused with the final MLP; h never written.
__attribute__((amdgpu_waves_per_eu(2, 4)))
__global__ __launch_bounds__(256) void k_dinvmlp(const float* __restrict__ h,
                                                 const float* __restrict__ g,
                                                 const float* __restrict__ cwp,
                                                 const float* __restrict__ wpk,
                                                 float* __restrict__ out) {
    __shared__ float2 sCSP[256];
    int b = blockIdx.x >> 8, x = blockIdx.x & 255;
    int y = threadIdx.x;
    fill_csp(sCSP, y, 256);
    float hreg[32];
#pragma unroll
    for (int i = 0; i < 32; ++i)
        hreg[i] = h[(((size_t)(b * 32 + i)) * 256 + x) * 256 + y];
    __syncthreads();
    float ck[12], sk[12];
#pragma unroll
    for (int ky = 1; ky < 12; ++ky) {
        int p = (ky * y) & 255;
        float2 cs2 = sCSP[p];
        ck[ky] = 2.0f * cs2.x; sk[ky] = 2.0f * cs2.y;
    }
    const float* gb = g + ((size_t)(b * 32) * 256 + x) * 24;
    const float* wb = cwp + 3 * 32 * 36;
    float v[32];
#pragma unroll
    for (int o = 0; o < 32; ++o) {
        const float* gp = gb + (size_t)o * 6144;   // uniform address
        const float* wp = wb + o * 36;             // uniform address
        float sc0 = gp[0], sc1 = 0.f, ss0 = 0.f, ss1 = 0.f;
#pragma unroll
        for (int ky = 1; ky < 12; ky += 2) {
            sc0 = __builtin_fmaf(gp[2 * ky], ck[ky], sc0);
            ss0 = __builtin_fmaf(gp[2 * ky + 1], sk[ky], ss0);
        }
#pragma unroll
        for (int ky = 2; ky < 12; ky += 2) {
            sc1 = __builtin_fmaf(gp[2 * ky], ck[ky], sc1);
            ss1 = __builtin_fmaf(gp[2 * ky + 1], sk[ky], ss1);
        }
        float spec = (sc0 + sc1) - (ss0 + ss1);
        float va0 = __builtin_fmaf(spec, 1.0f / 65536.0f, wp[32]);
        float va1 = 0.f, va2 = 0.f, va3 = 0.f;
#pragma unroll
        for (int i = 0; i < 32; i += 4) {
            va0 = __builtin_fmaf(hreg[i],     wp[i],     va0);
            va1 = __builtin_fmaf(hreg[i + 1], wp[i + 1], va1);
            va2 = __builtin_fmaf(hreg[i + 2], wp[i + 2], va2);
            va3 = __builtin_fmaf(hreg[i + 3], wp[i + 3], va3);
        }
        v[o] = (va0 + va1) + (va2 + va3);
    }
    float a0 = wpk[128 * 36 + 0], a1 = wpk[128 * 36 + 1], a2 = wpk[128 * 36 + 2];
#pragma unroll 2
    for (int k = 0; k < 128; ++k) {
        const float* wp = wpk + k * 36;            // uniform address
        float t0 = wp[32], t1 = 0.f, t2 = 0.f, t3 = 0.f;
#pragma unroll
        for (int i = 0; i < 32; i += 4) {
            t0 = __builtin_fmaf(v[i],     wp[i],     t0);
            t1 = __builtin_fmaf(v[i + 1], wp[i + 1], t1);
            t2 = __builtin_fmaf(v[i + 2], wp[i + 2], t2);
            t3 = __builtin_fmaf(v[i + 3], wp[i + 3], t3);
        }
        float t = fgelu((t0 + t1) + (t2 + t3));
        a0 = __builtin_fmaf(t, wp[33], a0);
        a1 = __builtin_fmaf(t, wp[34], a1);
        a2 = __builtin_fmaf(t, wp[35], a2);
    }
    out[(((size_t)b * 3 + 0) * 256 + x) * 256 + y] = a0;
    out[(((size_t)b * 3 + 1) * 256 + x) * 256 + y] = a1;
    out[(((size_t)b * 3 + 2) * 256 + x) * 256 + y] = a2;
}

extern "C" void kernel_launch(void* const* d_in, const int* in_sizes, int n_in,
                              void* d_out, int out_size, void* d_ws, size_t ws_size,
                              hipStream_t stream) {
    const float* xin  = (const float*)d_in[0];
    const float* pw   = (const float*)d_in[1];
    const float* pb   = (const float*)d_in[2];
    const float* sw1r = (const float*)d_in[3];
    const float* sw1i = (const float*)d_in[4];
    const float* sw2r = (const float*)d_in[5];
    const float* sw2i = (const float*)d_in[6];
    const float* cw   = (const float*)d_in[7];
    const float* cb   = (const float*)d_in[8];
    const float* w0   = (const float*)d_in[9];
    const float* b0   = (const float*)d_in[10];
    const float* w1   = (const float*)d_in[11];
    const float* b1   = (const float*)d_in[12];
    float* out = (float*)d_out;

    float* ws  = (float*)d_ws;
    float* wpk = ws;                  // 4624
    float* cwp = wpk + 4624;          // 4608
    float* h   = cwp + 4608;          // 8388608
    float* tmp = h + 8388608;         // 786432 (aliased with g)
    float* hfp = tmp + 786432;        // 294912
    float* g   = tmp;                 // alias

    k_init<<<1, 256, 0, stream>>>(w0, b0, w1, b1, cw, cb, wpk, cwp);
    k_liftf<<<1024, 256, 0, stream>>>(xin, pw, pb, h, tmp);
    for (int l = 0; l < 4; ++l) {
        k_dftx<<<512, 320, 0, stream>>>(tmp, hfp);
        k_mixcinv<<<128, 320, 0, stream>>>(hfp, sw1r, sw1i, sw2r, sw2i, g, l);
        if (l < 3)
            k_dinvf<<<1024, 256, 0, stream>>>(h, g, cwp, tmp, l);
        else
            k_dinvmlp<<<1024, 256, 0, stream>>>(h, g, cwp, wpk, out);
    }
}

// Round 9
// 302.543 us; speedup vs baseline: 1.0527x; 1.0527x over previous
//
#include <hip/hip_runtime.h>
#include <math.h>

// FNO2d: B=4, C=3, H=W=256, L=4, WIDTH=32, M1=M2=12
// R9: k_dinvmlp phase-split through thread-private LDS (sVv[y*33+o], pad-33 ->
// conflict-free, no barrier): phase A (bypass+spec) live set = hreg[32], phase
// B (MLP) live set = vreg[32]; the 34KB LDS also caps occupancy at 4 blocks/CU
// so the allocator budgets ~128 VGPR (same regime as k_dinvf, which compiles
// well). k_dinvf kept from R8 (waves_per_eu + 4-way ILP — it improved).
//
// ws layout (floats):
//   wpk [4624]     : packed MLP weights [k][32*w0 | b0 | w1*3], +b1 at end
//   cwp [4608]     : packed bypass weights [l][o][32*cw | cb | pad3]
//   h   [8388608]  : activations (B,32,H,W), in place per layer
//   tmp [786432]   : ky-DFT out (B,32,H,12) complex; ALIASED with g
//   hfp [294912]   : 4 x-partials of (B,32,24,12) complex

#define ANG0 0.024543692606170260f  // 2*pi/256

__device__ __forceinline__ float fgelu(float v) {
    // exact-GELU via A&S 7.1.26 erf approx, |err| <= 1.5e-7, branchless
    float u = v * 0.70710678118f;
    float a = fabsf(u);
    float t = __builtin_amdgcn_rcpf(__builtin_fmaf(0.3275911f, a, 1.0f));
    float p = t * __builtin_fmaf(t, __builtin_fmaf(t, __builtin_fmaf(t,
                  __builtin_fmaf(t, 1.061405429f, -1.453152027f),
                  1.421413741f), -0.284496736f), 0.254829592f);
    float e = __expf(-u * u);
    float er = __builtin_fmaf(-p, e, 1.0f);
    er = copysignf(er, u);
    return 0.5f * v * (1.0f + er);
}

__device__ __forceinline__ void fill_csp(float2* sCSP, int tid, int nthr) {
    for (int p = tid; p < 256; p += nthr)
        sCSP[p] = make_float2(cosf(p * ANG0), sinf(p * ANG0));
}

// ky-forward DFT over one (b,x) column held in sV[o*257 + y].
// Symmetric pairs, 4 independent accumulator chains.
__device__ __forceinline__ void ky_dft_tail(const float* sV, const float2* sCSP,
                                            float* tmp, int b, int x, int y) {
    for (int idx = y; idx < 384; idx += 256) {
        int o = idx / 12, ky = idx % 12;
        const float* vp = sV + o * 257;
        float v128 = vp[128];
        float aR0 = vp[0] + ((ky & 1) ? -v128 : v128);
        float aR1 = 0.f, aI0 = 0.f, aI1 = 0.f;
#pragma unroll 4
        for (int yy = 1; yy <= 125; yy += 2) {
            int p0 = (ky * yy) & 255;
            int p1 = (p0 + ky) & 255;
            float2 c0 = sCSP[p0], c1 = sCSP[p1];
            float fw0 = vp[yy],     bw0 = vp[256 - yy];
            float fw1 = vp[yy + 1], bw1 = vp[255 - yy];
            aR0 = __builtin_fmaf(fw0 + bw0, c0.x, aR0);
            aI0 = __builtin_fmaf(fw0 - bw0, -c0.y, aI0);
            aR1 = __builtin_fmaf(fw1 + bw1, c1.x, aR1);
            aI1 = __builtin_fmaf(fw1 - bw1, -c1.y, aI1);
        }
        {   // yy = 127 remainder
            int p = (ky * 127) & 255;
            float2 c = sCSP[p];
            float fw = vp[127], bw = vp[129];
            aR0 = __builtin_fmaf(fw + bw, c.x, aR0);
            aI0 = __builtin_fmaf(fw - bw, -c.y, aI0);
        }
        reinterpret_cast<float2*>(tmp + (((size_t)(b * 32 + o)) * 256 + x) * 24)[ky] =
            make_float2(aR0 + aR1, aI0 + aI1);
    }
}

__global__ void k_init(const float* __restrict__ w0, const float* __restrict__ b0,
                       const float* __restrict__ w1, const float* __restrict__ b1,
                       const float* __restrict__ cw, const float* __restrict__ cb,
                       float* __restrict__ wpk, float* __restrict__ cwp) {
    int t = threadIdx.x;
    for (int idx = t; idx < 128 * 36; idx += 256) {
        int k = idx / 36, j = idx - k * 36;
        float v;
        if (j < 32)       v = w0[j * 128 + k];
        else if (j == 32) v = b0[k];
        else              v = w1[k * 3 + (j - 33)];
        wpk[idx] = v;
    }
    if (t < 3) wpk[128 * 36 + t] = b1[t];
    for (int idx = t; idx < 4 * 32 * 36; idx += 256) {
        int lo = idx / 36, j = idx - lo * 36;
        int l = lo >> 5, o = lo & 31;
        float v = 0.f;
        if (j < 32)       v = cw[l * 1024 + j * 32 + o];
        else if (j == 32) v = cb[l * 32 + o];
        cwp[idx] = v;
    }
}

// Lift + ky-forward DFT for layer 0.
__global__ __launch_bounds__(256, 4) void k_liftf(const float* __restrict__ xin,
                                                  const float* __restrict__ pw,
                                                  const float* __restrict__ pb,
                                                  float* __restrict__ h,
                                                  float* __restrict__ tmp) {
    __shared__ float sV[32 * 257];
    __shared__ float2 sCSP[256];
    int b = blockIdx.x >> 8, x = blockIdx.x & 255, y = threadIdx.x;
    fill_csp(sCSP, y, 256);
    float f0 = xin[((b * 3 + 0) * 256 + x) * 256 + y];
    float f1 = xin[((b * 3 + 1) * 256 + x) * 256 + y];
    float f2 = xin[((b * 3 + 2) * 256 + x) * 256 + y];
    float gx = x * (1.0f / 255.0f), gy = y * (1.0f / 255.0f);
#pragma unroll
    for (int o = 0; o < 32; ++o) {
        float v = pb[o] + f0 * pw[o] + f1 * pw[32 + o] + f2 * pw[64 + o]
                + gx * pw[96 + o] + gy * pw[128 + o];
        h[((b * 32 + o) * 256 + x) * 256 + y] = v;
        sV[o * 257 + y] = v;
    }
    __syncthreads();
    ky_dft_tail(sV, sCSP, tmp, b, x, y);
}

// kx-forward DFT (4-way x-split): hfp[part][plane][kxi][ky]
__global__ __launch_bounds__(320) void k_dftx(const float* __restrict__ tmp,
                                              float* __restrict__ hfp) {
    __shared__ float sT[1536];
    __shared__ float2 sCSP[256];
    int plane = blockIdx.x >> 2, part = blockIdx.x & 3;
    int x0 = part * 64;
    int tid = threadIdx.x;
    fill_csp(sCSP, tid, 320);
    for (int idx = tid; idx < 1536; idx += 320)
        sT[idx] = tmp[(size_t)plane * 6144 + x0 * 24 + idx];
    __syncthreads();
    if (tid < 288) {
        int kxi = tid / 12, ky = tid % 12;
        int kxv = kxi < 12 ? kxi : 232 + kxi;
        float aR = 0.f, aI = 0.f;
        for (int xp = 0; xp < 64; ++xp) {
            int p = (kxv * (x0 + xp)) & 255;
            float2 cs2 = sCSP[p];
            float tr = sT[xp * 24 + 2 * ky], ti = sT[xp * 24 + 2 * ky + 1];
            aR += tr * cs2.x + ti * cs2.y;
            aI += ti * cs2.x - tr * cs2.y;
        }
        hfp[(((size_t)part * 128 + plane) * 24 + kxi) * 24 + 2 * ky]     = aR;
        hfp[(((size_t)part * 128 + plane) * 24 + kxi) * 24 + 2 * ky + 1] = aI;
    }
}

// Mode mix + kx-inverse, one block per (b,o).
__global__ __launch_bounds__(320) void k_mixcinv(const float* __restrict__ hfp,
                                                 const float* __restrict__ w1r,
                                                 const float* __restrict__ w1i,
                                                 const float* __restrict__ w2r,
                                                 const float* __restrict__ w2i,
                                                 float* __restrict__ g, int l) {
    __shared__ float sA[576];
    __shared__ float2 sCSP[256];
    int b = blockIdx.x >> 5, o = blockIdx.x & 31;
    int tid = threadIdx.x;
    fill_csp(sCSP, tid, 320);
    if (tid < 288) {
        int kxi = tid / 12, ky = tid % 12;
        const float *wr, *wi;
        int rk;
        if (kxi < 12) { wr = w1r; wi = w1i; rk = kxi; }
        else          { wr = w2r; wi = w2i; rk = kxi - 12; }
        size_t wbase = ((size_t)l * 32 * 32) * 144 + (size_t)o * 144 + rk * 12 + ky;
        size_t hbase = (((size_t)(b * 32)) * 24 + kxi) * 24 + 2 * ky;
        float aR = 0.f, aI = 0.f;
#pragma unroll 4
        for (int i = 0; i < 32; ++i) {
            float2 h0 = *reinterpret_cast<const float2*>(hfp + hbase + i * 576);
            float2 h1 = *reinterpret_cast<const float2*>(hfp + 73728 + hbase + i * 576);
            float2 h2 = *reinterpret_cast<const float2*>(hfp + 147456 + hbase + i * 576);
            float2 h3 = *reinterpret_cast<const float2*>(hfp + 221184 + hbase + i * 576);
            float hr = h0.x + h1.x + h2.x + h3.x;
            float hi = h0.y + h1.y + h2.y + h3.y;
            float wrv = wr[wbase + (size_t)i * 4608];
            float wiv = wi[wbase + (size_t)i * 4608];
            aR += hr * wrv - hi * wiv;
            aI += hr * wiv + hi * wrv;
        }
        sA[kxi * 24 + 2 * ky]     = aR;
        sA[kxi * 24 + 2 * ky + 1] = aI;
    }
    __syncthreads();
    if (tid < 256) {
        int x = tid;
        float out[24];
#pragma unroll
        for (int j = 0; j < 24; ++j) out[j] = 0.f;
        for (int kxi = 0; kxi < 24; ++kxi) {
            int kxv = kxi < 12 ? kxi : 232 + kxi;
            int p = (kxv * x) & 255;
            float2 cs2 = sCSP[p];
#pragma unroll
            for (int ky = 0; ky < 12; ++ky) {
                float ar = sA[kxi * 24 + 2 * ky], ai = sA[kxi * 24 + 2 * ky + 1];
                out[2 * ky]     += ar * cs2.x - ai * cs2.y;
                out[2 * ky + 1] += ar * cs2.y + ai * cs2.x;
            }
        }
        float* gp = g + ((size_t)(b * 32 + o)) * 6144 + x * 24;
#pragma unroll
        for (int j = 0; j < 24; ++j) gp[j] = out[j];
    }
}

// Layers 0..2: bypass+spectral+gelu, in-place h, + next-layer ky-DFT.
// g aliases tmp: all g reads precede the barrier; tail writes after.
__attribute__((amdgpu_waves_per_eu(2, 4)))
__global__ __launch_bounds__(256) void k_dinvf(float* __restrict__ h,
                                               const float* __restrict__ g,
                                               const float* __restrict__ cwp,
                                               float* __restrict__ tmp,
                                               int l) {
    __shared__ float sV[32 * 257];
    __shared__ float2 sCSP[256];
    int b = blockIdx.x >> 8, x = blockIdx.x & 255;
    int y = threadIdx.x;
    fill_csp(sCSP, y, 256);
    float hreg[32];
#pragma unroll
    for (int i = 0; i < 32; ++i)
        hreg[i] = h[(((size_t)(b * 32 + i)) * 256 + x) * 256 + y];
    __syncthreads();
    float ck[12], sk[12];
#pragma unroll
    for (int ky = 1; ky < 12; ++ky) {
        int p = (ky * y) & 255;
        float2 cs2 = sCSP[p];
        ck[ky] = 2.0f * cs2.x; sk[ky] = 2.0f * cs2.y;
    }
    const float* gb = g + ((size_t)(b * 32) * 256 + x) * 24;
    const float* wb = cwp + l * 32 * 36;
    for (int o = 0; o < 32; ++o) {
        const float* gp = gb + (size_t)o * 6144;   // uniform address
        const float* wp = wb + o * 36;             // uniform address
        float sc0 = gp[0], sc1 = 0.f, ss0 = 0.f, ss1 = 0.f;
#pragma unroll
        for (int ky = 1; ky < 12; ky += 2) {
            sc0 = __builtin_fmaf(gp[2 * ky], ck[ky], sc0);
            ss0 = __builtin_fmaf(gp[2 * ky + 1], sk[ky], ss0);
        }
#pragma unroll
        for (int ky = 2; ky < 12; ky += 2) {
            sc1 = __builtin_fmaf(gp[2 * ky], ck[ky], sc1);
            ss1 = __builtin_fmaf(gp[2 * ky + 1], sk[ky], ss1);
        }
        float spec = (sc0 + sc1) - (ss0 + ss1);
        float va0 = __builtin_fmaf(spec, 1.0f / 65536.0f, wp[32]);
        float va1 = 0.f, va2 = 0.f, va3 = 0.f;
#pragma unroll
        for (int i = 0; i < 32; i += 4) {
            va0 = __builtin_fmaf(hreg[i],     wp[i],     va0);
            va1 = __builtin_fmaf(hreg[i + 1], wp[i + 1], va1);
            va2 = __builtin_fmaf(hreg[i + 2], wp[i + 2], va2);
            va3 = __builtin_fmaf(hreg[i + 3], wp[i + 3], va3);
        }
        float v = (va0 + va1) + (va2 + va3);
        v = fgelu(v);
        h[(((size_t)(b * 32 + o)) * 256 + x) * 256 + y] = v;
        sV[o * 257 + y] = v;
    }
    __syncthreads();
    ky_dft_tail(sV, sCSP, tmp, b, x, y);
}

// Layer 3 (no gelu, no DFT) fused with the final MLP; h never written.
// Phase-split through thread-private LDS column sVv[y*33 + o] (pad-33:
// bank=(y+o)%32, conflict-free, no barrier needed). Phase A live set =
// hreg[32]; phase B live set = vreg[32]. 34KB LDS caps 4 blocks/CU ->
// allocator budgets ~128 VGPR.
__global__ __launch_bounds__(256) void k_dinvmlp(const float* __restrict__ h,
                                                 const float* __restrict__ g,
                                                 const float* __restrict__ cwp,
                                                 const float* __restrict__ wpk,
                                                 float* __restrict__ out) {
    __shared__ float sVv[256 * 33];
    __shared__ float2 sCSP[256];
    int b = blockIdx.x >> 8, x = blockIdx.x & 255;
    int y = threadIdx.x;
    fill_csp(sCSP, y, 256);
    float hreg[32];
#pragma unroll
    for (int i = 0; i < 32; ++i)
        hreg[i] = h[(((size_t)(b * 32 + i)) * 256 + x) * 256 + y];
    __syncthreads();
    float ck[12], sk[12];
#pragma unroll
    for (int ky = 1; ky < 12; ++ky) {
        int p = (ky * y) & 255;
        float2 cs2 = sCSP[p];
        ck[ky] = 2.0f * cs2.x; sk[ky] = 2.0f * cs2.y;
    }
    const float* gb = g + ((size_t)(b * 32) * 256 + x) * 24;
    const float* wb = cwp + 3 * 32 * 36;
    float* vcol = sVv + y * 33;
    for (int o = 0; o < 32; ++o) {
        const float* gp = gb + (size_t)o * 6144;   // uniform address
        const float* wp = wb + o * 36;             // uniform address
        float sc0 = gp[0], sc1 = 0.f, ss0 = 0.f, ss1 = 0.f;
#pragma unroll
        for (int ky = 1; ky < 12; ky += 2) {
            sc0 = __builtin_fmaf(gp[2 * ky], ck[ky], sc0);
            ss0 = __builtin_fmaf(gp[2 * ky + 1], sk[ky], ss0);
        }
#pragma unroll
        for (int ky = 2; ky < 12; ky += 2) {
            sc1 = __builtin_fmaf(gp[2 * ky], ck[ky], sc1);
            ss1 = __builtin_fmaf(gp[2 * ky + 1], sk[ky], ss1);
        }
        float spec = (sc0 + sc1) - (ss0 + ss1);
        float va0 = __builtin_fmaf(spec, 1.0f / 65536.0f, wp[32]);
        float va1 = 0.f, va2 = 0.f, va3 = 0.f;
#pragma unroll
        for (int i = 0; i < 32; i += 4) {
            va0 = __builtin_fmaf(hreg[i],     wp[i],     va0);
            va1 = __builtin_fmaf(hreg[i + 1], wp[i + 1], va1);
            va2 = __builtin_fmaf(hreg[i + 2], wp[i + 2], va2);
            va3 = __builtin_fmaf(hreg[i + 3], wp[i + 3], va3);
        }
        vcol[o] = (va0 + va1) + (va2 + va3);   // hreg dead after o==31
    }
    // Phase B: reload v column (thread-private, same-thread LDS ordering).
    float vreg[32];
#pragma unroll
    for (int i = 0; i < 32; ++i) vreg[i] = vcol[i];
    float a0 = wpk[128 * 36 + 0], a1 = wpk[128 * 36 + 1], a2 = wpk[128 * 36 + 2];
#pragma unroll 2
    for (int k = 0; k < 128; ++k) {
        const float* wp = wpk + k * 36;            // uniform address
        float t0 = wp[32], t1 = 0.f, t2 = 0.f, t3 = 0.f;
#pragma unroll
        for (int i = 0; i < 32; i += 4) {
            t0 = __builtin_fmaf(vreg[i],     wp[i],     t0);
            t1 = __builtin_fmaf(vreg[i + 1], wp[i + 1], t1);
            t2 = __builtin_fmaf(vreg[i + 2], wp[i + 2], t2);
            t3 = __builtin_fmaf(vreg[i + 3], wp[i + 3], t3);
        }
        float t = fgelu((t0 + t1) + (t2 + t3));
        a0 = __builtin_fmaf(t, wp[33], a0);
        a1 = __builtin_fmaf(t, wp[34], a1);
        a2 = __builtin_fmaf(t, wp[35], a2);
    }
    out[(((size_t)b * 3 + 0) * 256 + x) * 256 + y] = a0;
    out[(((size_t)b * 3 + 1) * 256 + x) * 256 + y] = a1;
    out[(((size_t)b * 3 + 2) * 256 + x) * 256 + y] = a2;
}

extern "C" void kernel_launch(void* const* d_in, const int* in_sizes, int n_in,
                              void* d_out, int out_size, void* d_ws, size_t ws_size,
                              hipStream_t stream) {
    const float* xin  = (const float*)d_in[0];
    const float* pw   = (const float*)d_in[1];
    const float* pb   = (const float*)d_in[2];
    const float* sw1r = (const float*)d_in[3];
    const float* sw1i = (const float*)d_in[4];
    const float* sw2r = (const float*)d_in[5];
    const float* sw2i = (const float*)d_in[6];
    const float* cw   = (const float*)d_in[7];
    const float* cb   = (const float*)d_in[8];
    const float* w0   = (const float*)d_in[9];
    const float* b0   = (const float*)d_in[10];
    const float* w1   = (const float*)d_in[11];
    const float* b1   = (const float*)d_in[12];
    float* out = (float*)d_out;

    float* ws  = (float*)d_ws;
    float* wpk = ws;                  // 4624
    float* cwp = wpk + 4624;          // 4608
    float* h   = cwp + 4608;          // 8388608
    float* tmp = h + 8388608;         // 786432 (aliased with g)
    float* hfp = tmp + 786432;        // 294912
    float* g   = tmp;                 // alias

    k_init<<<1, 256, 0, stream>>>(w0, b0, w1, b1, cw, cb, wpk, cwp);
    k_liftf<<<1024, 256, 0, stream>>>(xin, pw, pb, h, tmp);
    for (int l = 0; l < 4; ++l) {
        k_dftx<<<512, 320, 0, stream>>>(tmp, hfp);
        k_mixcinv<<<128, 320, 0, stream>>>(hfp, sw1r, sw1i, sw2r, sw2i, g, l);
        if (l < 3)
            k_dinvf<<<1024, 256, 0, stream>>>(h, g, cwp, tmp, l);
        else
            k_dinvmlp<<<1024, 256, 0, stream>>>(h, g, cwp, wpk, out);
    }
}